// Round 6
// baseline (521.120 us; speedup 1.0000x reference)
//
#include <hip/hip_runtime.h>

// GeneralLinear: x[8192,16,576] fp32 -> out[8192,16,9] fp32.
// out[n,o,col_l(e)] = (1/32) * sum_{c,u} x[n, c, off_l + u*d_l + e] * w_l[c*64+u, o]
//
// R10 = R9 resubmitted verbatim (Round 5 was an infra failure: container
// acquisition failed twice; no measurement was taken, so the R9 hypothesis
// is still pending).
//
// R9: fat stages + w-in-registers + depth-1 prefetch, no inline asm.
//  - 1024 blocks x 8 rows, 256 thr, 4 blocks/CU exact (LDS 36.9 KB, VGPR<=128).
//  - Thread = (r = lane&7, qs = lane>>3&1, oq = lane>>4), q = wv*2+qs.
//  - 16 stages (stage = channel c). Per stage: __syncthreads (its vmcnt(0)
//    is exactly "x(s) done", nothing extra in flight) -> issue x(s+1) DMA
//    into the dead buffer -> compute both u-halves h=0,1.
//  - x: 18 gather DMAs/stage (5/5/4/4 per wave) into [h][72 qc][8 r][4];
//    128 B contiguous per row per instr; 2 buffers, depth-1 (stage time
//    ~10 us >> 0.9 us HBM latency).
//  - w: NO LDS. 24 global float4 loads/thread/stage (2 x 64 B segments per
//    wave-instr, r 8-way broadcast-coalesced). Per-stage w slice = 12 KB,
//    L1-resident; whole w = 196 KB, L2-resident -> ~0 HBM.
//  - Epilogue: R8's proven 8-partial LDS reduction (slot stride 9 float4,
//    36864 B = exactly the x buffers) + single-owner float4 stores.

#define DIN   576
#define XROW  (16 * DIN)      // 9216 floats per x row
#define NCH   16              // stages
#define HFL   2304            // floats per u-half (72 qc x 8 r x 4)
#define BUF   (2 * HFL)       // 4608 floats per stage buffer
#define LDSF  (2 * BUF)       // 9216 floats = 36864 B -> 4 blocks/CU

__device__ __forceinline__ void dma16(const float* g, float* l) {
    __builtin_amdgcn_global_load_lds(
        (const __attribute__((address_space(1))) void*)g,
        (__attribute__((address_space(3))) void*)l, 16, 0, 0);
}

__device__ __forceinline__ void fma4(float4& a, float s, const float4 w) {
    a.x += s * w.x; a.y += s * w.y; a.z += s * w.z; a.w += s * w.w;
}

__global__ __launch_bounds__(256, 4) void glin_r9(
    const float* __restrict__ x,
    const float* __restrict__ w0,
    const float* __restrict__ w1,
    const float* __restrict__ w2,
    float* __restrict__ out)
{
    __shared__ __align__(16) float lds[LDSF];
#define LD4(i) (*(const float4*)&lds[(i)])
#define GW4(p, i) (*(const float4*)&(p)[(i)])

    const int tid  = threadIdx.x;
    const int lane = tid & 63;
    const int wv   = tid >> 6;
    const int r    = lane & 7;          // row within block
    const int qs   = (lane >> 3) & 1;   // u-quad sub-index
    const int oq   = lane >> 4;         // output quad
    const int q    = wv * 2 + qs;       // u-quad 0..7 within a half
    const int rowbase = blockIdx.x * 8;

    const float* xrow = x + (size_t)(rowbase + r) * XROW;   // per-lane (row)

    // x stage: 18 gather DMAs, wave wv issues [start, start+cnt):
    //   wv0: 0-4, wv1: 5-9, wv2: 10-13, wv3: 14-17  (wave-uniform branches)
    const int istart = (wv < 2) ? wv * 5 : 10 + (wv - 2) * 4;
    const int icnt   = (wv < 2) ? 5 : 4;
    auto issue_x = [&](int s) {
        float* db = &lds[(s & 1) * BUF];
        const float* xb = xrow + s * DIN;
#pragma unroll
        for (int k = 0; k < 5; ++k) {
            if (k < icnt) {
                const int i  = istart + k;
                const int h  = (i >= 9) ? 1 : 0;
                const int ii = i - 9 * h;
                const int qc = ii * 8 + (lane >> 3);
                const int col = (qc < 8)  ? (32 * h + 4 * qc)
                              : (qc < 32) ? (32 + 96 * h + 4 * qc)
                                          : (128 + 160 * h + 4 * qc);
                dma16(xb + col, db + h * HFL + ii * 256);
            }
        }
    };

    issue_x(0);

    float4 acc[9];
#pragma unroll
    for (int i = 0; i < 9; ++i) acc[i] = make_float4(0.f, 0.f, 0.f, 0.f);

    for (int s = 0; s < NCH; ++s) {
        __syncthreads();                 // vmcnt(0): exactly "x(s) landed"
        if (s + 1 < NCH) issue_x(s + 1); // into dead buffer (s+1)&1

        const int bo = (s & 1) * BUF;
#pragma unroll
        for (int h = 0; h < 2; ++h) {
            const int xo = bo + h * HFL + r * 4;
            // w row block for this (c, h, q): rows c*64 + 32h + 4q + j
            const int wrow = ((s * 64 + 32 * h + 4 * q) * 16) + oq * 4;
            {   // l0 -> acc[0]
                float4 a0 = GW4(w0, wrow), a1 = GW4(w0, wrow + 16),
                       a2 = GW4(w0, wrow + 32), a3 = GW4(w0, wrow + 48);
                float4 xq = LD4(xo + q * 32);
                fma4(acc[0], xq.x, a0); fma4(acc[0], xq.y, a1);
                fma4(acc[0], xq.z, a2); fma4(acc[0], xq.w, a3);
            }
            {   // l1 -> acc[1..3]
                float4 b0 = GW4(w1, wrow), b1 = GW4(w1, wrow + 16),
                       b2 = GW4(w1, wrow + 32), b3 = GW4(w1, wrow + 48);
                const int x1 = xo + (8 + 3 * q) * 32;
                float4 xa = LD4(x1), xbv = LD4(x1 + 32), xc = LD4(x1 + 64);
                fma4(acc[1], xa.x, b0); fma4(acc[2], xa.y, b0); fma4(acc[3], xa.z, b0);
                fma4(acc[1], xa.w, b1); fma4(acc[2], xbv.x, b1); fma4(acc[3], xbv.y, b1);
                fma4(acc[1], xbv.z, b2); fma4(acc[2], xbv.w, b2); fma4(acc[3], xc.x, b2);
                fma4(acc[1], xc.y, b3); fma4(acc[2], xc.z, b3); fma4(acc[3], xc.w, b3);
            }
            {   // l2 -> acc[4..8]
                float4 c0 = GW4(w2, wrow), c1 = GW4(w2, wrow + 16),
                       c2 = GW4(w2, wrow + 32), c3 = GW4(w2, wrow + 48);
                const int x2 = xo + (32 + 5 * q) * 32;
                float4 xa = LD4(x2), xbv = LD4(x2 + 32), xc = LD4(x2 + 64),
                       xd = LD4(x2 + 96), xe = LD4(x2 + 128);
                fma4(acc[4], xa.x, c0); fma4(acc[5], xa.y, c0); fma4(acc[6], xa.z, c0);
                fma4(acc[7], xa.w, c0); fma4(acc[8], xbv.x, c0);
                fma4(acc[4], xbv.y, c1); fma4(acc[5], xbv.z, c1); fma4(acc[6], xbv.w, c1);
                fma4(acc[7], xc.x, c1); fma4(acc[8], xc.y, c1);
                fma4(acc[4], xc.z, c2); fma4(acc[5], xc.w, c2); fma4(acc[6], xd.x, c2);
                fma4(acc[7], xd.y, c2); fma4(acc[8], xd.z, c2);
                fma4(acc[4], xd.w, c3); fma4(acc[5], xe.x, c3); fma4(acc[6], xe.y, c3);
                fma4(acc[7], xe.z, c3); fma4(acc[8], xe.w, c3);
            }
        }
    }

    // ---- once-per-block epilogue: 8-partial reduction + single-owner store ----
    // Slot stride 9 float4: 256 slots x 9 x 16 B = 36864 B = LDSF exactly.
    __syncthreads();                       // both x buffers dead
    {
        const int slot = (q * 8 + r) * 4 + oq;   // 0..255, unique per thread
#pragma unroll
        for (int col = 0; col < 9; ++col)
            *(float4*)&lds[(slot * 9 + col) * 4] = acc[col];
    }
    __syncthreads();
    if (wv == 0 && lane < 32) {
        const int rr = lane & 7, oqq = lane >> 3;
        const float sc = 1.0f / 32.0f;
        float f[36];
#pragma unroll
        for (int col = 0; col < 9; ++col) {
            float4 v = make_float4(0.f, 0.f, 0.f, 0.f);
#pragma unroll
            for (int p = 0; p < 8; ++p) {
                float4 t = LD4(((((p * 8 + rr) * 4 + oqq) * 9) + col) * 4);
                v.x += t.x; v.y += t.y; v.z += t.z; v.w += t.w;
            }
            f[0 * 9 + col] = v.x * sc;
            f[1 * 9 + col] = v.y * sc;
            f[2 * 9 + col] = v.z * sc;
            f[3 * 9 + col] = v.w * sc;
        }
        float* op = out + ((size_t)(rowbase + rr) * 16 + oqq * 4) * 9;
#pragma unroll
        for (int k = 0; k < 9; ++k)
            *(float4*)&op[k * 4] =
                make_float4(f[4 * k], f[4 * k + 1], f[4 * k + 2], f[4 * k + 3]);
    }
#undef LD4
#undef GW4
}

extern "C" void kernel_launch(void* const* d_in, const int* in_sizes, int n_in,
                              void* d_out, int out_size, void* d_ws, size_t ws_size,
                              hipStream_t stream) {
    (void)in_sizes; (void)n_in; (void)d_ws; (void)ws_size; (void)out_size;
    glin_r9<<<1024, 256, 0, stream>>>((const float*)d_in[0], (const float*)d_in[1],
                                      (const float*)d_in[2], (const float*)d_in[3],
                                      (float*)d_out);
}

// Round 7
// 419.843 us; speedup vs baseline: 1.2412x; 1.2412x over previous
//
#include <hip/hip_runtime.h>

// GeneralLinear: x[8192,16,576] fp32 -> out[8192,16,9] fp32.
// out[n,o,col_l(e)] = (1/32) * sum_{c,u} x[n, c, off_l + u*d_l + e] * w_l[c*64+u, o]
//
// R11: wave-autonomous pipeline — ZERO barriers in the main loop.
//  Diagnosis chain: R10 counters (VALU 9.6%, HBM 18%, conflicts ~0, occ 41%)
//  show all pipes idle; R4/R6/R8/R10 all cost ~13-15k cyc/stage vs ~1k of
//  work -> the common limiter is the barrier convoy, not any pipe. Also
//  R10 proved compute loads must be LDS (lgkmcnt), not global (vmcnt), or
//  they entangle with prefetch DMAs in the vmcnt FIFO and drain them.
//
//  - 2048 blocks x 4 rows; 4 waves/block, each wave fully independent:
//    wave wv owns u-quads {wv, wv+4, wv+8, wv+12} (qi = qs*4 + wv).
//    Lane = (r = lane&3, oq = (lane>>2)&3, qs = lane>>4). One u-quad/thread.
//  - Per stage s = channel c: wave DMAs its own x slice (3 instrs: 144 f4
//    + 48 pad) and its own w slice (3 instrs, one per w_l, 64 f4 each)
//    into WAVE-PRIVATE double-buffered LDS. Own counted vmcnt(6) certifies
//    [w(s),x(s)] landed while [w(s+1),x(s+1)] stay in flight; vmcnt(0)
//    only at s=15. Prefetch(s+2) issued after lgkmcnt(0) (own reads
//    retired -> buffer provably dead, program order, no barrier).
//  - LDS 49152 B -> 3 blocks/CU = 12 autonomous waves/CU. VGPR budget ~100.
//  - Layouts: x slot=(t*9+k) f4 (t=qs*4+r) -> (t+k)%8 bank-quads: 2-way,
//    free. w slot=(l*64+j*16+qs*4+oq) f4 -> (qs*4+oq)%8: 2-way, free.
//    oq-groups broadcast. DMA dests are linear 64-f4 runs (HW lane*16).
//  - Epilogue (only sync in kernel): shfl_xor(16,32) reduces qs in-wave;
//    lane<16 writes 1 partial/wave; 2 syncthreads; wave0 sums 4, stores.

#define DIN   576
#define XROW  (16 * DIN)
#define NCH   16
#define XBUF  768                  // floats: 192 f4 (144 data + 48 pad)
#define WBUF  768                  // floats: 192 f4 exact (3 l x 64)
#define PW    (2 * XBUF + 2 * WBUF)   // 3072 floats per wave
#define LDSF  (4 * PW)                // 12288 fl = 49152 B -> 3 blocks/CU

__device__ __forceinline__ void dma16(const float* g, float* l) {
    __builtin_amdgcn_global_load_lds(
        (const __attribute__((address_space(1))) void*)g,
        (__attribute__((address_space(3))) void*)l, 16, 0, 0);
}

__device__ __forceinline__ void fma4(float4& a, float s, const float4 w) {
    a.x += s * w.x; a.y += s * w.y; a.z += s * w.z; a.w += s * w.w;
}

__global__ __launch_bounds__(256, 3) void glin_async(
    const float* __restrict__ x,
    const float* __restrict__ w0,
    const float* __restrict__ w1,
    const float* __restrict__ w2,
    float* __restrict__ out)
{
    __shared__ __align__(16) float lds[LDSF];
#define LD4(i) (*(const float4*)&lds[(i)])

    const int tid  = threadIdx.x;
    const int lane = tid & 63;
    const int wv   = tid >> 6;
    const int r    = lane & 3;          // row within block
    const int oq   = (lane >> 2) & 3;   // output quad
    const int qs   = lane >> 4;         // which of the wave's 4 u-quads
    const int rowbase = blockIdx.x * 4;

    const int xbase = wv * PW;              // x bufs: xbase + p*XBUF
    const int wbase = wv * PW + 2 * XBUF;   // w bufs: wbase + p*WBUF

    // ---- per-lane DMA source offsets ----
    // x instr m: flat f4 j = m*64+lane (clamp 143; dups land in pad).
    //   t = j/9, k = j%9, rr = t&3, qv = (t>>2)*4 + wv.
    //   f4col: k=0 -> qv (l0) | k=1..3 -> 16+3*qv+(k-1) (l1)
    //          | k=4..8 -> 64+5*qv+(k-4) (l2).
    const float* bx[3];
#pragma unroll
    for (int m = 0; m < 3; ++m) {
        int j = m * 64 + lane; if (j > 143) j = 143;
        const int t = j / 9, k = j % 9;
        const int rr = t & 3, qv = (t >> 2) * 4 + wv;
        const int f4c = (k == 0) ? qv
                      : (k < 4)  ? (16 + 3 * qv + (k - 1))
                                 : (64 + 5 * qv + (k - 4));
        bx[m] = x + (size_t)(rowbase + rr) * XROW + f4c * 4;
    }
    // w instr l: lane -> (j = lane>>4, qk = (lane>>2)&3, oc = lane&3);
    //   u = 16*qk + 4*wv + j; src fl = (c*64+u)*16 + oc*4.
    const int wu   = 16 * ((lane >> 2) & 3) + 4 * wv + (lane >> 4);
    const int woff = wu * 16 + (lane & 3) * 4;

    auto issue = [&](int s) {
        const int p = s & 1;
        float* wx = &lds[xbase + p * XBUF];
        float* ww = &lds[wbase + p * WBUF];
        dma16(w0 + woff + s * 1024, ww);          // w group first (FIFO)
        dma16(w1 + woff + s * 1024, ww + 256);
        dma16(w2 + woff + s * 1024, ww + 512);
        dma16(bx[0] + s * DIN, wx);
        dma16(bx[1] + s * DIN, wx + 256);
        dma16(bx[2] + s * DIN, wx + 512);
    };

    issue(0);
    issue(1);

    float4 acc[9];
#pragma unroll
    for (int i = 0; i < 9; ++i) acc[i] = make_float4(0.f, 0.f, 0.f, 0.f);

    for (int s = 0; s < NCH; ++s) {
        // Own counted wait: queue = [w(s),x(s),w(s+1),x(s+1)] (12).
        // vmcnt(6) certifies group s landed; group s+1 stays in flight.
        if (s == NCH - 1) asm volatile("s_waitcnt vmcnt(0)" ::: "memory");
        else              asm volatile("s_waitcnt vmcnt(6)" ::: "memory");
        __builtin_amdgcn_sched_barrier(0);

        const int p  = s & 1;
        const int xo = xbase + p * XBUF + (qs * 4 + r) * 36;
        const int wo = wbase + p * WBUF + qs * 16 + oq * 4;
        {   // l0 -> acc[0]
            float4 xq = LD4(xo);
            float4 a0 = LD4(wo), a1 = LD4(wo + 64),
                   a2 = LD4(wo + 128), a3 = LD4(wo + 192);
            fma4(acc[0], xq.x, a0); fma4(acc[0], xq.y, a1);
            fma4(acc[0], xq.z, a2); fma4(acc[0], xq.w, a3);
        }
        {   // l1 -> acc[1..3]
            float4 b0 = LD4(wo + 256), b1 = LD4(wo + 320),
                   b2 = LD4(wo + 384), b3 = LD4(wo + 448);
            float4 xa = LD4(xo + 4), xbv = LD4(xo + 8), xc = LD4(xo + 12);
            fma4(acc[1], xa.x, b0); fma4(acc[2], xa.y, b0); fma4(acc[3], xa.z, b0);
            fma4(acc[1], xa.w, b1); fma4(acc[2], xbv.x, b1); fma4(acc[3], xbv.y, b1);
            fma4(acc[1], xbv.z, b2); fma4(acc[2], xbv.w, b2); fma4(acc[3], xc.x, b2);
            fma4(acc[1], xc.y, b3); fma4(acc[2], xc.z, b3); fma4(acc[3], xc.w, b3);
        }
        {   // l2 -> acc[4..8]
            float4 c0 = LD4(wo + 512), c1 = LD4(wo + 576),
                   c2 = LD4(wo + 640), c3 = LD4(wo + 704);
            float4 ya = LD4(xo + 16), yb = LD4(xo + 20), yc = LD4(xo + 24),
                   yd = LD4(xo + 28), ye = LD4(xo + 32);
            fma4(acc[4], ya.x, c0); fma4(acc[5], ya.y, c0); fma4(acc[6], ya.z, c0);
            fma4(acc[7], ya.w, c0); fma4(acc[8], yb.x, c0);
            fma4(acc[4], yb.y, c1); fma4(acc[5], yb.z, c1); fma4(acc[6], yb.w, c1);
            fma4(acc[7], yc.x, c1); fma4(acc[8], yc.y, c1);
            fma4(acc[4], yc.z, c2); fma4(acc[5], yc.w, c2); fma4(acc[6], yd.x, c2);
            fma4(acc[7], yd.y, c2); fma4(acc[8], yd.z, c2);
            fma4(acc[4], yd.w, c3); fma4(acc[5], ye.x, c3); fma4(acc[6], ye.y, c3);
            fma4(acc[7], ye.z, c3); fma4(acc[8], ye.w, c3);
        }

        // Prefetch s+2 into this stage's (now dead) buffers — own reads
        // must have RETIRED first (lgkmcnt(0), per-wave program order).
        if (s + 2 < NCH) {
            asm volatile("s_waitcnt lgkmcnt(0)" ::: "memory");
            __builtin_amdgcn_sched_barrier(0);
            issue(s + 2);
        }
    }

    // ---- epilogue: reduce qs in-wave, then 4 wave-partials via LDS ----
#pragma unroll
    for (int col = 0; col < 9; ++col) {
        acc[col].x += __shfl_xor(acc[col].x, 16);
        acc[col].y += __shfl_xor(acc[col].y, 16);
        acc[col].z += __shfl_xor(acc[col].z, 16);
        acc[col].w += __shfl_xor(acc[col].w, 16);
        acc[col].x += __shfl_xor(acc[col].x, 32);
        acc[col].y += __shfl_xor(acc[col].y, 32);
        acc[col].z += __shfl_xor(acc[col].z, 32);
        acc[col].w += __shfl_xor(acc[col].w, 32);
    }
    __syncthreads();                    // only now do waves interact
    if (lane < 16) {
        const int slot = wv * 16 + lane;       // 0..63
#pragma unroll
        for (int col = 0; col < 9; ++col)
            *(float4*)&lds[slot * 36 + col * 4] = acc[col];
    }
    __syncthreads();
    if (wv == 0 && lane < 16) {
        const int rr = lane & 3, oo = (lane >> 2) & 3;
        const float sc = 1.0f / 32.0f;
        float f[36];
#pragma unroll
        for (int col = 0; col < 9; ++col) {
            float4 v = make_float4(0.f, 0.f, 0.f, 0.f);
#pragma unroll
            for (int pp = 0; pp < 4; ++pp) {
                float4 t = LD4((pp * 16 + lane) * 36 + col * 4);
                v.x += t.x; v.y += t.y; v.z += t.z; v.w += t.w;
            }
            f[0 * 9 + col] = v.x * sc;
            f[1 * 9 + col] = v.y * sc;
            f[2 * 9 + col] = v.z * sc;
            f[3 * 9 + col] = v.w * sc;
        }
        float* op = out + ((size_t)(rowbase + rr) * 16 + oo * 4) * 9;
#pragma unroll
        for (int k = 0; k < 9; ++k)
            *(float4*)&op[k * 4] =
                make_float4(f[4 * k], f[4 * k + 1], f[4 * k + 2], f[4 * k + 3]);
    }
#undef LD4
}

extern "C" void kernel_launch(void* const* d_in, const int* in_sizes, int n_in,
                              void* d_out, int out_size, void* d_ws, size_t ws_size,
                              hipStream_t stream) {
    (void)in_sizes; (void)n_in; (void)d_ws; (void)ws_size; (void)out_size;
    glin_async<<<2048, 256, 0, stream>>>((const float*)d_in[0], (const float*)d_in[1],
                                         (const float*)d_in[2], (const float*)d_in[3],
                                         (float*)d_out);
}